// Round 16
// baseline (1452.626 us; speedup 1.0000x reference)
//
#include <hip/hip_runtime.h>

// LSTM: B=256, T=512, I=64, H=512, G=4H=2048.
// gates = W @ [h; x], W = [R | kernel^T], K = 576.
// R16: WAVE-SPLIT HALVES. 256 WGs x 256 thr; waves{0,1}=half0 -> group bid&7,
// waves{2,3}=half1 -> group (bid&7)+8. Each half: one 16-col gate-slice
// (sl = bid>>3, 0..31), 2 M-tiles/wave (144 W AGPRs, proven), own LDS
// buffers, own LDS generation-barriers (NO WG-wide barrier in the loop).
// The two chains' publish->detect RTTs hide under each other's compute (TLP).
// h exchange: TAGGED u32s ((s<<16)|bf16), relaxed agent-scope atomics,
// parity double-buffered, coalesced poll (R11), s_sleep backoff (R15).
#define TSTEPS 512
#define BATCH  256
#define ISZ    64
#define HSZ    512
#define GSZ    2048
#define NKT    18
#define BG     16
#define ROWU   608          // LDS row length in u16 (584 data + 24 pad)
#define PLANE64 65536       // u64 per parity plane: 256*512/2

typedef __attribute__((ext_vector_type(8))) short short8;
typedef __attribute__((ext_vector_type(4))) float f32x4;
typedef __attribute__((ext_vector_type(4))) unsigned int u32x4;
typedef unsigned long long u64t;

static __device__ __forceinline__ unsigned short f2bf(float f) {
    unsigned int u = __float_as_uint(f);
    return (unsigned short)((u + 0x7fffu + ((u >> 16) & 1u)) >> 16);  // RNE
}
static __device__ __forceinline__ float sig_(float x) {
    return 1.0f / (1.0f + __expf(-x));
}
static __device__ __forceinline__ float tanh_(float x) {
    float e = __expf(-2.0f * fabsf(x));
    float t = (1.0f - e) / (1.0f + e);
    return copysignf(t, x);
}
static __device__ __forceinline__ u64t ld_tag64(const u64t* p) {
    return __hip_atomic_load(p, __ATOMIC_RELAXED, __HIP_MEMORY_SCOPE_AGENT);
}
static __device__ __forceinline__ void st_tag64(u64t* p, u64t v) {
    __hip_atomic_store(p, v, __ATOMIC_RELAXED, __HIP_MEMORY_SCOPE_AGENT);
}

// Pack W = [R | kernel^T] (fp32) into bf16 MFMA A-fragment order. (unchanged)
// Frag t = ((jj*8 + m)*18 + kt)*64 + lane; row r = 16m + (lane&15);
// gate q = r&3; hco = r>>2; global row = q*512 + jj*32 + hco.
__global__ void pack_w(const float* __restrict__ R, const float* __restrict__ Kin,
                       unsigned short* __restrict__ wpack)
{
    const int t  = blockIdx.x * 256 + threadIdx.x;
    const int l  = t & 63;
    const int kt = (t >> 6) % NKT;
    const int m  = (t / (64 * NKT)) & 7;
    const int jj = t / (64 * NKT * 8);
    const int r   = 16 * m + (l & 15);
    const int q   = r & 3;
    const int hco = r >> 2;
    const int grow  = q * HSZ + jj * 32 + hco;
    const int kbase = kt * 32 + (l >> 4) * 8;
    unsigned int pk[4];
#pragma unroll
    for (int p = 0; p < 4; ++p) {
        const int k0 = kbase + 2 * p;
        const int k1 = k0 + 1;
        const float f0 = (k0 < HSZ) ? R[(size_t)grow * HSZ + k0]
                                    : Kin[(size_t)(k0 - HSZ) * GSZ + grow];
        const float f1 = (k1 < HSZ) ? R[(size_t)grow * HSZ + k1]
                                    : Kin[(size_t)(k1 - HSZ) * GSZ + grow];
        pk[p] = (unsigned)f2bf(f0) | ((unsigned)f2bf(f1) << 16);
    }
    uint4 v = make_uint4(pk[0], pk[1], pk[2], pk[3]);
    *reinterpret_cast<uint4*>(wpack + (size_t)t * 8) = v;
}

// Zero tagged h buffer each launch (tag 0 matches no step >= 1): replay-safe.
__global__ void zero_tags(u32x4* __restrict__ hb) {
    u32x4 z = {0u, 0u, 0u, 0u};
    hb[blockIdx.x * 256 + threadIdx.x] = z;
}

__global__ __launch_bounds__(256, 1) void lstm_persist(
    const unsigned short* __restrict__ wpack,
    const float* __restrict__ input_seq,
    const float* __restrict__ bias,
    unsigned int* __restrict__ tbuf,     // [2 parity][256 b][512 col] tagged u32
    float* __restrict__ hlast)
{
    __shared__ __align__(16) unsigned short lds_B[2][16][ROWU];  // per-half [b][k]
    __shared__ __align__(16) unsigned short lds_hn[2][16][24];   // per-half new-h
    __shared__ unsigned bcnt[2];                                 // half barriers
    const int tid = threadIdx.x;
    const int bid = blockIdx.x;          // 256 WGs
    const int p    = bid & 7;            // pair-set (XCD under round-robin)
    const int sl   = bid >> 3;           // gate-slice 0..31 (16 h-cols)
    const int w4   = tid >> 6;
    const int half = w4 >> 1;            // waves{0,1}->0, {2,3}->1
    const int hw   = w4 & 1;             // wave within half
    const int htid = tid & 127;
    const int l  = tid & 63;
    const int bb = l & 15;
    const int lg = l >> 4;
    const int g  = p + 8 * half;         // this half's batch-group

    const int jjold = sl >> 1;           // 32-col slice index in pack_w layout
    const int m0 = (sl & 1) * 4 + 2 * hw;
    const int m1 = m0 + 1;

    // ---- one-time: W fragments -> registers, PINNED into AGPRs (144) ----
    short8 wA[NKT], wB[NKT];
#pragma unroll
    for (int kt = 0; kt < NKT; ++kt) {
        wA[kt] = *reinterpret_cast<const short8*>(
            wpack + (((size_t)(jjold * 8 + m0) * NKT + kt) * 64 + l) * 8);
        wB[kt] = *reinterpret_cast<const short8*>(
            wpack + (((size_t)(jjold * 8 + m1) * NKT + kt) * 64 + l) * 8);
    }
#pragma unroll
    for (int kt = 0; kt < NKT; ++kt) {
        asm volatile("" : "+a"(wA[kt]));
        asm volatile("" : "+a"(wB[kt]));
    }
    const int lc0 = 8 * hw + lg;         // local col within 16-col slice
    const int lc1 = lc0 + 4;
    const int gh0 = sl * 16 + lc0, gh1 = sl * 16 + lc1;   // global h-cols
    float bs0[4], bs1[4];
#pragma unroll
    for (int qg = 0; qg < 4; ++qg) {
        bs0[qg] = bias[qg * HSZ + gh0];
        bs1[qg] = bias[qg * HSZ + gh1];
    }

    float c0 = 0.f, c1 = 0.f;

    // x staging (per half, 128 thr): sb = htid&15, chunk sc2 = htid>>4 (8 cols)
    const int sb = htid & 15, sc2 = htid >> 4;
    const float* xbase = input_seq + (size_t)(g * BG + sb) * (TSTEPS * ISZ) + sc2 * 8;
    float4 xa = *reinterpret_cast<const float4*>(xbase);
    float4 xc = *reinterpret_cast<const float4*>(xbase + 4);

    const u64t* const hb0 = reinterpret_cast<const u64t*>(tbuf);
    const u64t* const hb1 = reinterpret_cast<const u64t*>(tbuf) + PLANE64;
    // poll (per half): rr = htid>>4 (8 rows/pass, 2 passes), cch = htid&15;
    // 16 loads stride 16 u64 per pass (128B contiguous per 16-lane phase).
    const int rr = htid >> 4, cch = htid & 15;
    // publish (per half): b_ = htid>>3, pr = htid&7 -> 1 u64 (2 cols)
    const int b_ = htid >> 3, pr = htid & 7;
    const size_t pdst = (size_t)(g * BG + b_) * 256 + sl * 8 + pr;

    if (tid < 2) bcnt[tid] = 0;
    __syncthreads();                     // covers bcnt init; last WG-wide sync
    unsigned gen = 0;
    volatile unsigned* bc = &bcnt[half];

#define HBAR()                                                                 \
    {                                                                          \
        asm volatile("s_waitcnt lgkmcnt(0)" ::: "memory");                     \
        ++gen;                                                                 \
        if (l == 0)                                                            \
            __hip_atomic_fetch_add((unsigned*)bc, 1u, __ATOMIC_RELAXED,        \
                                   __HIP_MEMORY_SCOPE_WORKGROUP);              \
        while (*bc < 2u * gen) { }                                             \
        asm volatile("s_waitcnt lgkmcnt(0)" ::: "memory");                     \
        __builtin_amdgcn_sched_barrier(0);                                     \
    }

    for (int s = 0; s < TSTEPS; ++s) {
        // stage x(s); prefetch x(s+1)
        {
            uint2 p0, p1;
            p0.x = (unsigned)f2bf(xa.x) | ((unsigned)f2bf(xa.y) << 16);
            p0.y = (unsigned)f2bf(xa.z) | ((unsigned)f2bf(xa.w) << 16);
            p1.x = (unsigned)f2bf(xc.x) | ((unsigned)f2bf(xc.y) << 16);
            p1.y = (unsigned)f2bf(xc.z) | ((unsigned)f2bf(xc.w) << 16);
            *reinterpret_cast<uint2*>(&lds_B[half][sb][HSZ + sc2 * 8]) = p0;
            *reinterpret_cast<uint2*>(&lds_B[half][sb][HSZ + sc2 * 8 + 4]) = p1;
            if (s + 1 < TSTEPS) {
                xa = *reinterpret_cast<const float4*>(xbase + (size_t)(s + 1) * ISZ);
                xc = *reinterpret_cast<const float4*>(xbase + (size_t)(s + 1) * ISZ + 4);
            }
        }
        // ---- acquire h(s): poll tagged data, 2 passes of 8 rows ----
        if (s > 0) {
            const u64t* plane = (s & 1) ? hb1 : hb0;
            const u64t want = ((u64t)(unsigned)s << 48) | ((u64t)(unsigned)s << 16);
#pragma unroll
            for (int j = 0; j < 2; ++j) {
                const int row = rr + 8 * j;
                const u64t* src = plane + (size_t)(g * BG + row) * 256 + cch;
                u64t v[16];
                bool ok;
                bool first = true;
                do {
                    if (!first) __builtin_amdgcn_s_sleep(2);
                    first = false;
                    ok = true;
#pragma unroll
                    for (int i = 0; i < 16; ++i)
                        v[i] = ld_tag64(src + (size_t)i * 16);
#pragma unroll
                    for (int i = 0; i < 16; ++i)
                        ok = ok && ((v[i] & 0xFFFF0000FFFF0000ull) == want);
                } while (!ok);
#pragma unroll
                for (int i = 0; i < 16; ++i) {
                    const unsigned d = (unsigned)(v[i] & 0xFFFFu) |
                                       ((unsigned)(v[i] >> 16) & 0xFFFF0000u);
                    *reinterpret_cast<unsigned*>(&lds_B[half][row][i * 32 + cch * 2]) = d;
                }
            }
        } else {
#pragma unroll
            for (int j = 0; j < 2; ++j)
#pragma unroll
                for (int i = 0; i < 16; ++i)
                    *reinterpret_cast<unsigned*>(
                        &lds_B[half][rr + 8 * j][i * 32 + cch * 2]) = 0u;
        }
        HBAR();   // B: this half's staging complete

        // ---- MFMA: acc initialized with bias ----
        f32x4 acc0 = {bs0[0], bs0[1], bs0[2], bs0[3]};
        f32x4 acc1 = {bs1[0], bs1[1], bs1[2], bs1[3]};
#pragma unroll
        for (int kt = 0; kt < NKT; ++kt) {
            const short8 bf = *reinterpret_cast<const short8*>(
                &lds_B[half][bb][kt * 32 + lg * 8]);
            acc0 = __builtin_amdgcn_mfma_f32_16x16x32_bf16(wA[kt], bf, acc0, 0, 0, 0);
            acc1 = __builtin_amdgcn_mfma_f32_16x16x32_bf16(wB[kt], bf, acc1, 0, 0, 0);
        }

        // ---- lane-local cell update ----
        const float fg0 = sig_(acc0[0]);
        const float ig0 = sig_(acc0[1]);
        const float cp0 = tanh_(acc0[2]);
        const float og0 = sig_(acc0[3]);
        c0 = fg0 * c0 + ig0 * cp0;
        const float h0v = og0 * tanh_(c0);
        const float fg1 = sig_(acc1[0]);
        const float ig1 = sig_(acc1[1]);
        const float cp1 = tanh_(acc1[2]);
        const float og1 = sig_(acc1[3]);
        c1 = fg1 * c1 + ig1 * cp1;
        const float h1v = og1 * tanh_(c1);

        if (s == TSTEPS - 1) {
            hlast[(size_t)(g * BG + bb) * HSZ + gh0] = h0v;
            hlast[(size_t)(g * BG + bb) * HSZ + gh1] = h1v;
            break;   // uniform within the half
        }
        lds_hn[half][bb][lc0] = f2bf(h0v);
        lds_hn[half][bb][lc1] = f2bf(h1v);
        HBAR();   // C: hn ready; lds_B MFMA reads done

        // ---- publish h(s+1): coalesced tagged u64 atomic stores ----
        {
            const unsigned h2 = *reinterpret_cast<const unsigned*>(
                &lds_hn[half][b_][pr * 2]);
            const unsigned t16 = (unsigned)(s + 1) << 16;
            const unsigned lo = (h2 & 0xFFFFu) | t16;
            const unsigned hi = (h2 >> 16) | t16;
            const u64t tagged = ((u64t)hi << 32) | (u64t)lo;
            u64t* dst = (u64t*)(tbuf) + (size_t)((s + 1) & 1) * PLANE64 + pdst;
            st_tag64(dst, tagged);
        }
    }
#undef HBAR
}

// out[b] = h_last[b,:] . Wout + bout
__global__ void out_kernel(const float* __restrict__ hlast,
                           const float* __restrict__ wout,
                           const float* __restrict__ bout,
                           float* __restrict__ out)
{
    const int b = blockIdx.x;
    const int l = threadIdx.x;
    float p = 0.f;
    for (int k = l; k < HSZ; k += 64)
        p += hlast[(size_t)b * HSZ + k] * wout[k];
    for (int off = 32; off > 0; off >>= 1)
        p += __shfl_down(p, off, 64);
    if (l == 0) out[b] = p + bout[0];
}

extern "C" void kernel_launch(void* const* d_in, const int* in_sizes, int n_in,
                              void* d_out, int out_size, void* d_ws, size_t ws_size,
                              hipStream_t stream) {
    const float* input_seq = (const float*)d_in[0];
    const float* Kin       = (const float*)d_in[1];
    const float* R         = (const float*)d_in[2];
    const float* bias      = (const float*)d_in[3];
    const float* Wout      = (const float*)d_in[4];
    const float* bout      = (const float*)d_in[5];
    float* out = (float*)d_out;

    char* ws = (char*)d_ws;
    unsigned short* wpack = (unsigned short*)(ws);                    // 2,359,296 B
    unsigned int* tbuf    = (unsigned int*)(ws + 2359296);            // 1,048,576 B
    float* hlast          = (float*)(ws + 2359296 + 1048576);         //   524,288 B

    zero_tags<<<dim3(256), dim3(256), 0, stream>>>((u32x4*)tbuf);
    pack_w<<<dim3(576), dim3(256), 0, stream>>>(R, Kin, wpack);
    lstm_persist<<<dim3(256), dim3(256), 0, stream>>>(
        wpack, input_seq, bias, tbuf, hlast);
    out_kernel<<<dim3(256), dim3(64), 0, stream>>>(hlast, Wout, bout, out);
}